// Round 21
// baseline (159.983 us; speedup 1.0000x reference)
//
#include <hip/hip_runtime.h>
#include <math.h>
#include <limits.h>

#define Bb 32
#define Tt 16384
#define Cc 128
#define Dd 256
#define Pp 2048
#define GMAX 4096
#define TP 16

// pid as XLA-jit computes it: divide(t,7) -> multiply(t, fl(1/7)).
// fl(1/7) = 0x3E124925. VERIFIED passing combination (R19) — do not touch.
__device__ __forceinline__ int PID(float t) {
  return (int)floorf(t * 0.14285714924335479736328125f);
}

// ---------------- Kernel A: XLA ReduceWindowRewriter radix-16 cumsum ----------
// VERIFIED producer replica (R19, absmax 0.0039). Unchanged.
__global__ __launch_bounds__(256) void scan_k(const float* __restrict__ td,
                                              int* __restrict__ starts,
                                              int* __restrict__ ngroups) {
  __shared__ float buf[Tt];
  __shared__ float S0[1024], P0[1024];
  __shared__ float S1[64],  P1[64];
  __shared__ float P2s[4];
  __shared__ int   cnt[256];

  const int b = blockIdx.x;
  const int tid = threadIdx.x;
  const float* row = td + (size_t)b * Tt;

  const float4* r4 = (const float4*)row;
  float4* b4 = (float4*)buf;
  for (int i = tid; i < Tt / 4; i += 256) b4[i] = r4[i];
  __syncthreads();

  for (int k = tid; k < 1024; k += 256) {
    const float* p = buf + k * 16;
    float s = p[0];
    #pragma unroll
    for (int j = 1; j < 16; ++j) s += p[j];
    S0[k] = s;
  }
  __syncthreads();

  if (tid < 64) {
    const float* p = S0 + tid * 16;
    float s = p[0];
    #pragma unroll
    for (int j = 1; j < 16; ++j) s += p[j];
    S1[tid] = s;
  }
  __syncthreads();

  if (tid == 0) {
    float run = 0.f;
    for (int m = 0; m < 4; ++m) {
      const float* p = S1 + m * 16;
      float s = p[0];
      #pragma unroll
      for (int j = 1; j < 16; ++j) s += p[j];
      run = (m == 0) ? s : run + s;
      P2s[m] = run;
    }
  }
  __syncthreads();

  if (tid < 64) {
    const int k2 = tid >> 4, j1 = tid & 15;
    const float* p = S1 + (k2 << 4);
    float s = p[0];
    for (int j = 1; j <= j1; ++j) s += p[j];
    P1[tid] = (k2 == 0) ? s : s + P2s[k2 - 1];
  }
  __syncthreads();

  for (int k = tid; k < 1024; k += 256) {
    const int k1 = k >> 4, j = k & 15;
    const float* p = S0 + (k1 << 4);
    float s = p[0];
    for (int jj = 1; jj <= j; ++jj) s += p[jj];
    P0[k] = (k1 == 0) ? s : s + P1[k1 - 1];
  }
  __syncthreads();

  const int base = tid * 64;
  int pprev0;
  if (tid == 0) pprev0 = INT_MIN;
  else {
    const int k = 4 * tid - 1;
    const float t = (k == 0) ? S0[0] : S0[k] + P0[k - 1];
    pprev0 = PID(t);
  }

  int pprev = pprev0, count = 0;
  for (int tk = 0; tk < 4; ++tk) {
    const int k = 4 * tid + tk;
    const float carry = (k == 0) ? 0.f : P0[k - 1];
    const float* p = buf + k * 16;
    float s = 0.f;
    #pragma unroll
    for (int j = 0; j < 16; ++j) {
      s = (j == 0) ? p[0] : s + p[j];
      const float t = (k == 0) ? s : s + carry;
      const int pid = PID(t);
      count += (pid != pprev);
      pprev = pid;
    }
  }
  cnt[tid] = count;
  __syncthreads();
  if (tid == 0) {
    int run = 0;
    for (int k = 0; k < 256; ++k) { int c = cnt[k]; cnt[k] = run; run += c; }
  }
  __syncthreads();

  int r = cnt[tid];
  pprev = pprev0;
  int* stb = starts + b * GMAX;
  for (int tk = 0; tk < 4; ++tk) {
    const int k = 4 * tid + tk;
    const float carry = (k == 0) ? 0.f : P0[k - 1];
    const float* p = buf + k * 16;
    float s = 0.f;
    #pragma unroll
    for (int j = 0; j < 16; ++j) {
      s = (j == 0) ? p[0] : s + p[j];
      const float t = (k == 0) ? s : s + carry;
      const int pid = PID(t);
      if (pid != pprev) stb[r++] = k * 16 + j;
      pprev = pid;
    }
  }
  if (tid == 255) {
    ngroups[b] = r;
    stb[r] = Tt;
  }
}

// ---------------- Kernel B: fused group-mean + linear projection --------------
// Mean phase: 4 groups per wave processed CONCURRENTLY (fused loop, 4
// predicated float4 loads per iteration -> ~8 loads in flight per lane vs 2
// in the serial-group version). lane = (row-parity r2, channel-quad cq).
// Mean tile patch-major [16][128]: conflict-free vector writes + uniform b128
// broadcast reads in the FMA phase.
__global__ __launch_bounds__(256) void embed_k(const float* __restrict__ x,
                                               const float* __restrict__ Wm,
                                               const float* __restrict__ bias,
                                               const int* __restrict__ starts,
                                               const int* __restrict__ ngroups,
                                               float* __restrict__ out_patches,
                                               float* __restrict__ out_valid) {
  const int blk = blockIdx.x;
  const int b = blk >> 7;
  const int pt = (blk & 127) * TP;
  const int tid = threadIdx.x;
  const int ng = ngroups[b];
  const int off = Pp - ng;             // slot p valid iff p >= off

  const float bias_v = bias[tid];
  const size_t obase = ((size_t)b * Pp + pt) * Dd + tid;

  if (tid < TP)
    out_valid[(size_t)b * Pp + pt + tid] = (pt + tid >= off) ? 1.0f : 0.0f;

  if (pt + TP <= off) {                // whole tile is padding -> bias
    #pragma unroll
    for (int j = 0; j < TP; ++j) out_patches[obase + (size_t)j * Dd] = bias_v;
    return;
  }

  __shared__ float mean_l[TP][Cc];     // 8 KB, patch-major
  const int wave = tid >> 6, lane = tid & 63;
  const int r2 = lane >> 5;            // row parity
  const int cq = lane & 31;            // channel quad -> channels 4cq..4cq+3
  const int* st = starts + b * GMAX;
  const int g0 = pt + wave * 4 - off;  // group of this wave's first patch

  // preload the 5 boundaries (independent scalar loads, issued together)
  int sg[5];
  #pragma unroll
  for (int k = 0; k < 5; ++k) {
    const int g = g0 + k;
    sg[k] = (g >= 0 && g <= ng) ? st[g] : 0;
  }

  float4 acc[4];
  int n[4];
  #pragma unroll
  for (int k = 0; k < 4; ++k) {
    acc[k] = make_float4(0.f, 0.f, 0.f, 0.f);
    n[k] = (g0 + k >= 0) ? (sg[k + 1] - sg[k]) : 0;
  }
  const int nmax = max(max(n[0], n[1]), max(n[2], n[3]));

  const float* xb = x + ((size_t)b * Tt) * Cc + 4 * cq;
  for (int i = r2; i < nmax; i += 2) { // fused: one load per group per iter
    #pragma unroll
    for (int k = 0; k < 4; ++k) {
      if (i < n[k]) {
        const float4 v = *(const float4*)(xb + (size_t)(sg[k] + i) * Cc);
        acc[k].x += v.x; acc[k].y += v.y; acc[k].z += v.z; acc[k].w += v.w;
      }
    }
  }

  #pragma unroll
  for (int k = 0; k < 4; ++k) {
    float4 a = acc[k];
    a.x += __shfl_xor(a.x, 32);        // merge row parities
    a.y += __shfl_xor(a.y, 32);
    a.z += __shfl_xor(a.z, 32);
    a.w += __shfl_xor(a.w, 32);
    if (r2 == 0) {
      float4 m = make_float4(0.f, 0.f, 0.f, 0.f);
      if (n[k] > 0) {
        const float fn = (float)n[k];
        m = make_float4(a.x / fn, a.y / fn, a.z / fn, a.w / fn);
      }
      *(float4*)(&mean_l[wave * 4 + k][4 * cq]) = m;  // conflict-free write
    }
  }
  __syncthreads();

  float accd[16];
  #pragma unroll
  for (int j = 0; j < 16; ++j) accd[j] = 0.f;

  const float* wp = Wm + tid;          // thread owns column d = tid
  for (int q = 0; q < Cc / 4; ++q) {   // c-quad loop
    const float w0 = wp[(4 * q + 0) * Dd];
    const float w1 = wp[(4 * q + 1) * Dd];
    const float w2 = wp[(4 * q + 2) * Dd];
    const float w3 = wp[(4 * q + 3) * Dd];
    #pragma unroll
    for (int j = 0; j < 16; ++j) {
      const float4 m = *(const float4*)(&mean_l[j][4 * q]);  // uniform b128
      float a = accd[j];
      a = fmaf(m.x, w0, a);
      a = fmaf(m.y, w1, a);
      a = fmaf(m.z, w2, a);
      a = fmaf(m.w, w3, a);
      accd[j] = a;
    }
  }

  #pragma unroll
  for (int j = 0; j < 16; ++j)
    out_patches[obase + (size_t)j * Dd] = accd[j] + bias_v;
}

extern "C" void kernel_launch(void* const* d_in, const int* in_sizes, int n_in,
                              void* d_out, int out_size, void* d_ws, size_t ws_size,
                              hipStream_t stream) {
  const float* x    = (const float*)d_in[0];
  const float* td   = (const float*)d_in[1];
  const float* Wm   = (const float*)d_in[2];
  const float* bias = (const float*)d_in[3];
  float* out = (float*)d_out;

  int* starts  = (int*)d_ws;
  int* ngroups = (int*)((char*)d_ws + (size_t)Bb * GMAX * 4);

  scan_k<<<Bb, 256, 0, stream>>>(td, starts, ngroups);
  embed_k<<<Bb * (Pp / TP), 256, 0, stream>>>(x, Wm, bias, starts, ngroups,
                                              out, out + (size_t)Bb * Pp * Dd);
}

// Round 22
// 148.708 us; speedup vs baseline: 1.0758x; 1.0758x over previous
//
#include <hip/hip_runtime.h>
#include <math.h>
#include <limits.h>

#define Bb 32
#define Tt 16384
#define Cc 128
#define Dd 256
#define Pp 2048
#define GMAX 4096
#define TP 16

// pid as XLA-jit computes it: divide(t,7) -> multiply(t, fl(1/7)).
// fl(1/7) = 0x3E124925. VERIFIED passing combination (R19) — do not touch.
__device__ __forceinline__ int PID(float t) {
  return (int)floorf(t * 0.14285714924335479736328125f);
}

// ---------------- Kernel A: XLA ReduceWindowRewriter radix-16 cumsum ----------
// VERIFIED producer replica (R19, absmax 0.0039). Unchanged.
__global__ __launch_bounds__(256) void scan_k(const float* __restrict__ td,
                                              int* __restrict__ starts,
                                              int* __restrict__ ngroups) {
  __shared__ float buf[Tt];
  __shared__ float S0[1024], P0[1024];
  __shared__ float S1[64],  P1[64];
  __shared__ float P2s[4];
  __shared__ int   cnt[256];

  const int b = blockIdx.x;
  const int tid = threadIdx.x;
  const float* row = td + (size_t)b * Tt;

  const float4* r4 = (const float4*)row;
  float4* b4 = (float4*)buf;
  for (int i = tid; i < Tt / 4; i += 256) b4[i] = r4[i];
  __syncthreads();

  for (int k = tid; k < 1024; k += 256) {
    const float* p = buf + k * 16;
    float s = p[0];
    #pragma unroll
    for (int j = 1; j < 16; ++j) s += p[j];
    S0[k] = s;
  }
  __syncthreads();

  if (tid < 64) {
    const float* p = S0 + tid * 16;
    float s = p[0];
    #pragma unroll
    for (int j = 1; j < 16; ++j) s += p[j];
    S1[tid] = s;
  }
  __syncthreads();

  if (tid == 0) {
    float run = 0.f;
    for (int m = 0; m < 4; ++m) {
      const float* p = S1 + m * 16;
      float s = p[0];
      #pragma unroll
      for (int j = 1; j < 16; ++j) s += p[j];
      run = (m == 0) ? s : run + s;
      P2s[m] = run;
    }
  }
  __syncthreads();

  if (tid < 64) {
    const int k2 = tid >> 4, j1 = tid & 15;
    const float* p = S1 + (k2 << 4);
    float s = p[0];
    for (int j = 1; j <= j1; ++j) s += p[j];
    P1[tid] = (k2 == 0) ? s : s + P2s[k2 - 1];
  }
  __syncthreads();

  for (int k = tid; k < 1024; k += 256) {
    const int k1 = k >> 4, j = k & 15;
    const float* p = S0 + (k1 << 4);
    float s = p[0];
    for (int jj = 1; jj <= j; ++jj) s += p[jj];
    P0[k] = (k1 == 0) ? s : s + P1[k1 - 1];
  }
  __syncthreads();

  const int base = tid * 64;
  int pprev0;
  if (tid == 0) pprev0 = INT_MIN;
  else {
    const int k = 4 * tid - 1;
    const float t = (k == 0) ? S0[0] : S0[k] + P0[k - 1];
    pprev0 = PID(t);
  }

  int pprev = pprev0, count = 0;
  for (int tk = 0; tk < 4; ++tk) {
    const int k = 4 * tid + tk;
    const float carry = (k == 0) ? 0.f : P0[k - 1];
    const float* p = buf + k * 16;
    float s = 0.f;
    #pragma unroll
    for (int j = 0; j < 16; ++j) {
      s = (j == 0) ? p[0] : s + p[j];
      const float t = (k == 0) ? s : s + carry;
      const int pid = PID(t);
      count += (pid != pprev);
      pprev = pid;
    }
  }
  cnt[tid] = count;
  __syncthreads();
  if (tid == 0) {
    int run = 0;
    for (int k = 0; k < 256; ++k) { int c = cnt[k]; cnt[k] = run; run += c; }
  }
  __syncthreads();

  int r = cnt[tid];
  pprev = pprev0;
  int* stb = starts + b * GMAX;
  for (int tk = 0; tk < 4; ++tk) {
    const int k = 4 * tid + tk;
    const float carry = (k == 0) ? 0.f : P0[k - 1];
    const float* p = buf + k * 16;
    float s = 0.f;
    #pragma unroll
    for (int j = 0; j < 16; ++j) {
      s = (j == 0) ? p[0] : s + p[j];
      const float t = (k == 0) ? s : s + carry;
      const int pid = PID(t);
      if (pid != pprev) stb[r++] = k * 16 + j;
      pprev = pid;
    }
  }
  if (tid == 255) {
    ngroups[b] = r;
    stb[r] = Tt;
  }
}

// ---------------- Kernel B1: group means, one wave per patch slot -------------
// Grid B*P one-wave blocks (65536): tiny blocks -> 32 waves/CU resident, load
// latency hidden by TLP (the R19-R21 fused kernel had ~8 blocks/CU and was
// latency-bound at ~165us regardless of inner structure).
// lane = (row-parity r2, channel-quad cq); float4 loads; shfl merge; means
// written to global [B][P][Cc]; invalid slots = zeros (-> gemm emits bias).
__global__ __launch_bounds__(64) void means_k(const float* __restrict__ x,
                                              const int* __restrict__ starts,
                                              const int* __restrict__ ngroups,
                                              float* __restrict__ means) {
  const int blk = blockIdx.x;
  const int b = blk >> 11;             // / Pp
  const int p = blk & (Pp - 1);
  const int lane = threadIdx.x;        // 0..63
  const int ng = ngroups[b];
  const int off = Pp - ng;
  const int g = p - off;
  float* mp = means + ((size_t)b * Pp + p) * Cc;

  if (g < 0) {                         // padding slot -> zero mean
    *(float2*)(mp + 2 * lane) = make_float2(0.f, 0.f);
    return;
  }

  const int* st = starts + b * GMAX;
  const int s = st[g], e = st[g + 1];
  const int n = e - s;
  const int r2 = lane >> 5;            // row parity
  const int cq = lane & 31;            // channel quad

  const float* xp = x + ((size_t)b * Tt + s) * Cc + 4 * cq;
  float4 a0 = make_float4(0.f, 0.f, 0.f, 0.f);
  float4 a1 = make_float4(0.f, 0.f, 0.f, 0.f);
  int i = r2;
  for (; i + 2 < n; i += 4) {          // 2 independent chains, 2 loads in flight
    const float4 v0 = *(const float4*)(xp + (size_t)i * Cc);
    const float4 v1 = *(const float4*)(xp + (size_t)(i + 2) * Cc);
    a0.x += v0.x; a0.y += v0.y; a0.z += v0.z; a0.w += v0.w;
    a1.x += v1.x; a1.y += v1.y; a1.z += v1.z; a1.w += v1.w;
  }
  if (i < n) {
    const float4 v = *(const float4*)(xp + (size_t)i * Cc);
    a0.x += v.x; a0.y += v.y; a0.z += v.z; a0.w += v.w;
  }
  a0.x += a1.x; a0.y += a1.y; a0.z += a1.z; a0.w += a1.w;
  a0.x += __shfl_xor(a0.x, 32);
  a0.y += __shfl_xor(a0.y, 32);
  a0.z += __shfl_xor(a0.z, 32);
  a0.w += __shfl_xor(a0.w, 32);
  if (r2 == 0) {
    const float fn = (float)n;
    *(float4*)(mp + 4 * cq) = make_float4(a0.x / fn, a0.y / fn, a0.z / fn, a0.w / fn);
  }
}

// ---------------- Kernel B2: dense projection out = means*W + b ---------------
// TP=16 patches/block (keeps W L2 traffic at 536 MB). Coalesced 8KB LDS stage
// of means, then thread-owns-d FMA loop (uniform b128 broadcasts, no conflicts).
__global__ __launch_bounds__(256) void gemm_k(const float* __restrict__ means,
                                              const float* __restrict__ Wm,
                                              const float* __restrict__ bias,
                                              const int* __restrict__ ngroups,
                                              float* __restrict__ out_patches,
                                              float* __restrict__ out_valid) {
  const int blk = blockIdx.x;
  const int b = blk >> 7;
  const int pt = (blk & 127) * TP;
  const int tid = threadIdx.x;
  const int ng = ngroups[b];
  const int off = Pp - ng;

  const float bias_v = bias[tid];
  const size_t obase = ((size_t)b * Pp + pt) * Dd + tid;

  if (tid < TP)
    out_valid[(size_t)b * Pp + pt + tid] = (pt + tid >= off) ? 1.0f : 0.0f;

  if (pt + TP <= off) {                // whole tile is padding -> bias
    #pragma unroll
    for (int j = 0; j < TP; ++j) out_patches[obase + (size_t)j * Dd] = bias_v;
    return;
  }

  __shared__ float mean_l[TP][Cc];     // 8 KB
  {                                    // coalesced stage: 2 float4 per thread
    const float4* src = (const float4*)(means + ((size_t)b * Pp + pt) * Cc);
    float4* dst = (float4*)&mean_l[0][0];
    dst[tid] = src[tid];
    dst[tid + 256] = src[tid + 256];
  }
  __syncthreads();

  float acc[16];
  #pragma unroll
  for (int j = 0; j < 16; ++j) acc[j] = 0.f;

  const float* wp = Wm + tid;          // thread owns column d = tid
  for (int q = 0; q < Cc / 4; ++q) {
    const float w0 = wp[(4 * q + 0) * Dd];
    const float w1 = wp[(4 * q + 1) * Dd];
    const float w2 = wp[(4 * q + 2) * Dd];
    const float w3 = wp[(4 * q + 3) * Dd];
    #pragma unroll
    for (int j = 0; j < 16; ++j) {
      const float4 m = *(const float4*)(&mean_l[j][4 * q]);  // uniform b128
      float a = acc[j];
      a = fmaf(m.x, w0, a);
      a = fmaf(m.y, w1, a);
      a = fmaf(m.z, w2, a);
      a = fmaf(m.w, w3, a);
      acc[j] = a;
    }
  }

  #pragma unroll
  for (int j = 0; j < 16; ++j)
    out_patches[obase + (size_t)j * Dd] = acc[j] + bias_v;
}

extern "C" void kernel_launch(void* const* d_in, const int* in_sizes, int n_in,
                              void* d_out, int out_size, void* d_ws, size_t ws_size,
                              hipStream_t stream) {
  const float* x    = (const float*)d_in[0];
  const float* td   = (const float*)d_in[1];
  const float* Wm   = (const float*)d_in[2];
  const float* bias = (const float*)d_in[3];
  float* out = (float*)d_out;

  int*   starts  = (int*)d_ws;                              // 512 KB
  int*   ngroups = (int*)((char*)d_ws + 524288);            // 128 B
  float* means   = (float*)((char*)d_ws + (1 << 20));       // 33.5 MB @ 1MB

  scan_k<<<Bb, 256, 0, stream>>>(td, starts, ngroups);
  means_k<<<Bb * Pp, 64, 0, stream>>>(x, starts, ngroups, means);
  gemm_k<<<Bb * (Pp / TP), 256, 0, stream>>>(means, Wm, bias, ngroups,
                                             out, out + (size_t)Bb * Pp * Dd);
}